// Round 3
// baseline (266.531 us; speedup 1.0000x reference)
//
#include <hip/hip_runtime.h>

// Patch_Embed_Rotate: per-16x16-patch conditional transpose.
// out[b,c,hi*16+i,wi*16+j] = mask[b,wi,hi] ? x[b,c,hi*16+j,wi*16+i]
//                                          : x[b,c,hi*16+i,wi*16+j]
// B=256, C=3, H=W=224, P=16.
//
// R2 lesson: strip-streaming through LDS with 12 __syncthreads/block ran at
// 2.5 TB/s with EVERYTHING idle (VALU 3.5%, conflicts 5%) — the per-phase
// s_waitcnt vmcnt(0)+s_barrier drain serializes the memory pipe. This version
// has NO LDS and NO barriers: the 16x16 transpose is done in-wave.
//
// Unit = 4 consecutive patches (global patch number n = hi*14+wi, 49 quads
// per image-channel exactly). 64 lanes = 4 patches x 16 lanes; each lane owns
// a 4x4 sub-block (4 float4 regs). Patch transpose = swap sub-block coords
// (ds_bpermute with lane' = 16p + 4*beta + alpha) + transposed element
// indexing at use (pure register renaming): out[r].elem[e] = B[e].elem[r].
// Loads/stores: instr rho covers 4 rows x 256 B contiguous segments.

#define NPATCH 14

__device__ __forceinline__ float bperm(int idx, float s) {
    return __int_as_float(__builtin_amdgcn_ds_bpermute(idx, __float_as_int(s)));
}

__global__ __launch_bounds__(256) void patch_rotate_kernel(
    const float* __restrict__ x,
    const int*   __restrict__ mask,
    float*       __restrict__ out)
{
    const int tid  = threadIdx.x;
    const int lane = tid & 63;
    const int wv   = tid >> 6;
    const int w    = blockIdx.x * 4 + wv;      // wave id, [0, 18816)

    const int p  = lane >> 4;                  // patch within quad, 0..3
    const int a  = (lane >> 2) & 3;            // sub-block row, 0..3
    const int bb = lane & 3;                   // sub-block col, 0..3
    const int lp = (lane & 48) | (bb << 2) | a;   // transposed partner lane
    const int idx = lp << 2;                   // bpermute byte index

    #pragma unroll
    for (int uu = 0; uu < 2; ++uu) {
        const int u   = 2 * w + uu;            // quad-unit id, [0, 37632)
        const int img = u / 49;                // b*3 + c
        const int q   = u % 49;
        const int n   = 4 * q + p;             // global patch number, 0..195
        const int hi  = n / NPATCH;
        const int wi  = n % NPATCH;
        const int b   = img / 3;

        const int row = hi * 16 + 4 * a;       // rows row..row+3 via regs
        const int col = wi * 16 + 4 * bb;
        const size_t base = ((size_t)img * 224 + row) * 224 + col;

        // 4 independent coalesced loads (4 rows x 256B segments per instr)
        const float4 v0 = *(const float4*)(x + base);
        const float4 v1 = *(const float4*)(x + base + 224);
        const float4 v2 = *(const float4*)(x + base + 448);
        const float4 v3 = *(const float4*)(x + base + 672);

        // per-patch mask (16 lanes share each address)
        const int m = mask[(b * NPATCH + wi) * NPATCH + hi];

        // gather transposed partner's 4 regs (16x ds_bpermute_b32, no LDS mem)
        float4 B0, B1, B2, B3;
        B0.x = bperm(idx, v0.x); B0.y = bperm(idx, v0.y);
        B0.z = bperm(idx, v0.z); B0.w = bperm(idx, v0.w);
        B1.x = bperm(idx, v1.x); B1.y = bperm(idx, v1.y);
        B1.z = bperm(idx, v1.z); B1.w = bperm(idx, v1.w);
        B2.x = bperm(idx, v2.x); B2.y = bperm(idx, v2.y);
        B2.z = bperm(idx, v2.z); B2.w = bperm(idx, v2.w);
        B3.x = bperm(idx, v3.x); B3.y = bperm(idx, v3.y);
        B3.z = bperm(idx, v3.z); B3.w = bperm(idx, v3.w);

        // out reg r element e = B[e].elem[r]  (4x4 in-register transpose)
        float4 r0 = v0, r1 = v1, r2 = v2, r3 = v3;
        if (m) {
            r0 = make_float4(B0.x, B1.x, B2.x, B3.x);
            r1 = make_float4(B0.y, B1.y, B2.y, B3.y);
            r2 = make_float4(B0.z, B1.z, B2.z, B3.z);
            r3 = make_float4(B0.w, B1.w, B2.w, B3.w);
        }

        // coalesced stores, same addressing as loads
        *(float4*)(out + base)       = r0;
        *(float4*)(out + base + 224) = r1;
        *(float4*)(out + base + 448) = r2;
        *(float4*)(out + base + 672) = r3;
    }
}

extern "C" void kernel_launch(void* const* d_in, const int* in_sizes, int n_in,
                              void* d_out, int out_size, void* d_ws, size_t ws_size,
                              hipStream_t stream) {
    const float* x    = (const float*)d_in[0];
    const int*   mask = (const int*)d_in[1];
    float*       out  = (float*)d_out;

    // 37632 quad-units, 2 per wave, 4 waves/block -> 4704 blocks exactly.
    patch_rotate_kernel<<<4704, 256, 0, stream>>>(x, mask, out);
}

// Round 4
// 251.724 us; speedup vs baseline: 1.0588x; 1.0588x over previous
//
#include <hip/hip_runtime.h>

// Patch_Embed_Rotate: per-16x16-patch conditional transpose.
// out[b,c,hi*16+i,wi*16+j] = mask[b,wi,hi] ? x[b,c,hi*16+j,wi*16+i]
//                                          : x[b,c,hi*16+i,wi*16+j]
// B=256, C=3, H=W=224, P=16.
//
// R3 post-mortem: three radically different kernels (64B-segment, fully
// contiguous+LDS, bpermute in-register) ALL pin at 2.5-3.3 TB/s with every
// pipe idle, while the harness fill hits 6.6 TB/s in the same run. Theory:
// the 588 MB 0xAA poison fill leaves L3 full of dirty lines; our ~308 MB of
// cache allocations evict them -> ~250 MB hidden writeback drain inside our
// window ((78+154+250)/92.7us ~= 5.2 TB/s: memory system actually near cap).
// Fix: NON-TEMPORAL loads/stores (nt flag, no L2/L3 allocation) -> never
// evict the poison lines -> drain deferred out of our window.
//
// Structure (verified correct in R3): unit = 4 consecutive patches
// (n = hi*14+wi, 49 quads per image-channel exactly). 64 lanes = 4 patches x
// 16 lanes; each lane owns a 4x4 sub-block (4 float4 regs). Patch transpose =
// ds_bpermute lane swap (lane' = 16p+4*beta+alpha) + transposed element
// indexing (register renaming): out[r].elem[e] = B[e].elem[r].

#define NPATCH 14

typedef float f4 __attribute__((ext_vector_type(4)));   // true vector type
                                                        // (nontemporal builtins
                                                        //  require vector/scalar)

__device__ __forceinline__ float bperm(int idx, float s) {
    return __int_as_float(__builtin_amdgcn_ds_bpermute(idx, __float_as_int(s)));
}

__global__ __launch_bounds__(256) void patch_rotate_kernel(
    const float* __restrict__ x,
    const int*   __restrict__ mask,
    float*       __restrict__ out)
{
    const int tid  = threadIdx.x;
    const int lane = tid & 63;
    const int wv   = tid >> 6;
    const int w    = blockIdx.x * 4 + wv;      // wave id, [0, 18816)

    const int p  = lane >> 4;                  // patch within quad, 0..3
    const int a  = (lane >> 2) & 3;            // sub-block row, 0..3
    const int bb = lane & 3;                   // sub-block col, 0..3
    const int lp = (lane & 48) | (bb << 2) | a;   // transposed partner lane
    const int idx = lp << 2;                   // bpermute byte index

    #pragma unroll
    for (int uu = 0; uu < 2; ++uu) {
        const int u   = 2 * w + uu;            // quad-unit id, [0, 37632)
        const int img = u / 49;                // b*3 + c
        const int q   = u % 49;
        const int n   = 4 * q + p;             // global patch number, 0..195
        const int hi  = n / NPATCH;
        const int wi  = n % NPATCH;
        const int b   = img / 3;

        const int row = hi * 16 + 4 * a;
        const int col = wi * 16 + 4 * bb;
        const size_t base = ((size_t)img * 224 + row) * 224 + col;

        // non-temporal loads: no L2/L3 allocation, don't evict poison lines
        const f4 v0 = __builtin_nontemporal_load((const f4*)(x + base));
        const f4 v1 = __builtin_nontemporal_load((const f4*)(x + base + 224));
        const f4 v2 = __builtin_nontemporal_load((const f4*)(x + base + 448));
        const f4 v3 = __builtin_nontemporal_load((const f4*)(x + base + 672));

        // per-patch mask (16 lanes share each address) — cached load, tiny
        const int m = mask[(b * NPATCH + wi) * NPATCH + hi];

        // gather transposed partner's 4 regs (16x ds_bpermute_b32, no LDS mem)
        f4 B0, B1, B2, B3;
        B0.x = bperm(idx, v0.x); B0.y = bperm(idx, v0.y);
        B0.z = bperm(idx, v0.z); B0.w = bperm(idx, v0.w);
        B1.x = bperm(idx, v1.x); B1.y = bperm(idx, v1.y);
        B1.z = bperm(idx, v1.z); B1.w = bperm(idx, v1.w);
        B2.x = bperm(idx, v2.x); B2.y = bperm(idx, v2.y);
        B2.z = bperm(idx, v2.z); B2.w = bperm(idx, v2.w);
        B3.x = bperm(idx, v3.x); B3.y = bperm(idx, v3.y);
        B3.z = bperm(idx, v3.z); B3.w = bperm(idx, v3.w);

        // out reg r element e = B[e].elem[r]  (4x4 in-register transpose)
        f4 r0 = v0, r1 = v1, r2 = v2, r3 = v3;
        if (m) {
            r0.x = B0.x; r0.y = B1.x; r0.z = B2.x; r0.w = B3.x;
            r1.x = B0.y; r1.y = B1.y; r1.z = B2.y; r1.w = B3.y;
            r2.x = B0.z; r2.y = B1.z; r2.z = B2.z; r2.w = B3.z;
            r3.x = B0.w; r3.y = B1.w; r3.z = B2.w; r3.w = B3.w;
        }

        // non-temporal stores: write-through, no allocation
        __builtin_nontemporal_store(r0, (f4*)(out + base));
        __builtin_nontemporal_store(r1, (f4*)(out + base + 224));
        __builtin_nontemporal_store(r2, (f4*)(out + base + 448));
        __builtin_nontemporal_store(r3, (f4*)(out + base + 672));
    }
}

extern "C" void kernel_launch(void* const* d_in, const int* in_sizes, int n_in,
                              void* d_out, int out_size, void* d_ws, size_t ws_size,
                              hipStream_t stream) {
    const float* x    = (const float*)d_in[0];
    const int*   mask = (const int*)d_in[1];
    float*       out  = (float*)d_out;

    // 37632 quad-units, 2 per wave, 4 waves/block -> 4704 blocks exactly.
    patch_rotate_kernel<<<4704, 256, 0, stream>>>(x, mask, out);
}